// Round 1
// baseline (17.008 us; speedup 1.0000x reference)
//
#include <hip/hip_runtime.h>

// GMMGradient: B=16384 samples, N=32 keypoints, K=16 components, D=3.
// out[0 .. B*N*D)          = sigmoid((pdf-40)/7.5) repeated 3x per (b,n)
// out[B*N*D .. 2*B*N*D)    = grad/|grad| * exp((5500-|grad|)/1100)
//
// Strategy: one kernel. Each block computes all 512 (n,k) {precision, const}
// sets into LDS (layout [k][j][n] -> bank = n = lane&31, conflict-free
// broadcast), then each thread processes R=4 samples sharing one n so the
// 160 LDS const reads amortize 4x.

#define BB 16384
#define NN 32
#define KK 16

#define LOG2E   1.4426950408889634f
#define LN2PI   1.8378770664093453f   // ln(2*pi)
// fold s = 0.5*log2e into precision so comp = exp2(cp - d^T P' d)
#define S_FOLD  0.7213475204444817f   // 0.5 * log2(e)
#define INV_S   1.3862943611198906f   // 1/S_FOLD = 2*ln2

#if defined(__has_builtin)
#if __has_builtin(__builtin_amdgcn_exp2f)
#define EXP2F(x) __builtin_amdgcn_exp2f(x)
#endif
#endif
#ifndef EXP2F
#define EXP2F(x) exp2f(x)
#endif

__global__ __launch_bounds__(256) void gmm_grad_kernel(
    const float* __restrict__ kps,      // [B,N,3]
    const float* __restrict__ means,    // [N,K,3]
    const float* __restrict__ covs,     // [N,K,3,3]
    const float* __restrict__ weights,  // [N,K]
    float* __restrict__ out)            // [2*B*N*3]
{
    // consts[(k*10 + j)*32 + n]: j = m0,m1,m2,p00,p01,p02,p11,p12,p22,cp
    __shared__ float consts[KK * 10 * 32];
    const int tid = threadIdx.x;
    const int n = tid & 31;

    // ---- setup: cofactor inverse of SPD 3x3, fold scales ----
    {
        const int k1 = tid >> 5;  // 0..7; handle k1 and k1+8
#pragma unroll
        for (int kk = 0; kk < 2; ++kk) {
            const int k = k1 + kk * 8;
            const int p = n * KK + k;
            const float* C = covs + p * 9;
            const float a = C[0], b = C[1], c = C[2];
            const float d = C[4], e = C[5], f = C[8];
            const float i00 = d * f - e * e;
            const float i01 = c * e - b * f;
            const float i02 = b * e - c * d;
            const float i11 = a * f - c * c;
            const float i12 = b * c - a * e;
            const float i22 = a * d - b * b;
            const float det = a * i00 + b * i01 + c * i02;  // > 0 (SPD)
            const float rs = S_FOLD / det;
            const float logdet = __logf(det);
            const float w = weights[p];
            const float cp = (__logf(w) - 0.5f * (3.0f * LN2PI + logdet)) * LOG2E;
            const float* m = means + p * 3;
            float* dst = &consts[k * 10 * 32 + n];
            dst[0 * 32] = m[0];
            dst[1 * 32] = m[1];
            dst[2 * 32] = m[2];
            dst[3 * 32] = i00 * rs;
            dst[4 * 32] = i01 * rs;
            dst[5 * 32] = i02 * rs;
            dst[6 * 32] = i11 * rs;
            dst[7 * 32] = i12 * rs;
            dst[8 * 32] = i22 * rs;
            dst[9 * 32] = cp;
        }
    }
    __syncthreads();

    // ---- main: 4 samples per thread, same n (pair = blk*1024 + r*256 + tid,
    // 256 % 32 == 0 so n is invariant across r) ----
    const long pair0 = (long)blockIdx.x * 1024 + tid;

    float x0[4], x1[4], x2[4];
#pragma unroll
    for (int r = 0; r < 4; ++r) {
        const float* src = kps + (pair0 + r * 256) * 3;
        x0[r] = src[0];
        x1[r] = src[1];
        x2[r] = src[2];
    }

    float pdf[4] = {0.f, 0.f, 0.f, 0.f};
    float g0[4] = {0.f, 0.f, 0.f, 0.f};
    float g1[4] = {0.f, 0.f, 0.f, 0.f};
    float g2[4] = {0.f, 0.f, 0.f, 0.f};

#pragma unroll
    for (int k = 0; k < KK; ++k) {
        const float* L = &consts[k * 10 * 32 + n];
        const float m0 = L[0 * 32], m1 = L[1 * 32], m2 = L[2 * 32];
        const float p00 = L[3 * 32], p01 = L[4 * 32], p02 = L[5 * 32];
        const float p11 = L[6 * 32], p12 = L[7 * 32], p22 = L[8 * 32];
        const float cp = L[9 * 32];
#pragma unroll
        for (int r = 0; r < 4; ++r) {
            const float d0 = x0[r] - m0;
            const float d1 = x1[r] - m1;
            const float d2 = x2[r] - m2;
            // pd' = (0.5*log2e) * Sigma^{-1} d   (scale folded into P')
            const float pd0 = fmaf(p00, d0, fmaf(p01, d1, p02 * d2));
            const float pd1 = fmaf(p01, d0, fmaf(p11, d1, p12 * d2));
            const float pd2 = fmaf(p02, d0, fmaf(p12, d1, p22 * d2));
            const float mh = fmaf(pd0, d0, fmaf(pd1, d1, pd2 * d2));
            const float ec = EXP2F(cp - mh);  // = w_k * N(x; mu, Sigma)
            pdf[r] += ec;
            g0[r] = fmaf(ec, pd0, g0[r]);
            g1[r] = fmaf(ec, pd1, g1[r]);
            g2[r] = fmaf(ec, pd2, g2[r]);
        }
    }

    const long half = (long)BB * NN * 3;
#pragma unroll
    for (int r = 0; r < 4; ++r) {
        const long pair = pair0 + r * 256;
        // density: sigmoid((pdf - 40)/7.5)
        const float z = (pdf[r] - 40.0f) * (1.0f / 7.5f);
        const float dens = 1.0f / (1.0f + __expf(-z));
        // gradient: true grad = -gs/s; direction = -gs/|gs| (s cancels);
        // gnorm_true = |gs| * (2 ln2)
        const float q2 = fmaf(g0[r], g0[r], fmaf(g1[r], g1[r], g2[r] * g2[r]));
        const float q = sqrtf(q2);
        const float gnorm = q * INV_S;
        const float mag = __expf((5500.0f - gnorm) * (1.0f / 1100.0f));
        const float coef = -mag / q;
        float* od = out + pair * 3;
        od[0] = dens;
        od[1] = dens;
        od[2] = dens;
        float* og = out + half + pair * 3;
        og[0] = g0[r] * coef;
        og[1] = g1[r] * coef;
        og[2] = g2[r] * coef;
    }
}

extern "C" void kernel_launch(void* const* d_in, const int* in_sizes, int n_in,
                              void* d_out, int out_size, void* d_ws, size_t ws_size,
                              hipStream_t stream) {
    const float* kps = (const float*)d_in[0];      // [B,N,3]
    const float* means = (const float*)d_in[1];    // [N,K,3]
    const float* covs = (const float*)d_in[2];     // [N,K,3,3]
    const float* weights = (const float*)d_in[3];  // [N,K]
    float* out = (float*)d_out;

    // B*N = 524288 pairs; 1024 pairs/block (256 threads x 4)
    const int grid = (BB * NN) / 1024;  // 512
    gmm_grad_kernel<<<grid, 256, 0, stream>>>(kps, means, covs, weights, out);
}

// Round 2
// 16.204 us; speedup vs baseline: 1.0496x; 1.0496x over previous
//
#include <hip/hip_runtime.h>

// GMMGradient: B=16384 samples, N=32 keypoints, K=16 components, D=3.
// out[0 .. B*N*D)          = sigmoid((pdf-40)/7.5) repeated 3x per (b,n)
// out[B*N*D .. 2*B*N*D)    = grad/|grad| * exp((5500-|grad|)/1100)
//
// R1: r=2 samples/thread (grid 1024 -> 4 waves/SIMD, was 2), constants packed
// [k][n][10] read as 5x ds_read_b64 (2-way bank alias = free), kps loads
// issued before the setup phase to overlap HBM latency with inversion+barrier.

#define BB 16384
#define NN 32
#define KK 16
#define RR 2   // samples per thread

#define LOG2E   1.4426950408889634f
#define LN2PI   1.8378770664093453f   // ln(2*pi)
// fold s = 0.5*log2e into precision so comp = exp2(cp - d^T P' d)
#define S_FOLD  0.7213475204444817f   // 0.5 * log2(e)
#define INV_S   1.3862943611198906f   // 1/S_FOLD = 2*ln2

#if defined(__has_builtin)
#if __has_builtin(__builtin_amdgcn_exp2f)
#define EXP2F(x) __builtin_amdgcn_exp2f(x)
#endif
#endif
#ifndef EXP2F
#define EXP2F(x) exp2f(x)
#endif

__global__ __launch_bounds__(256) void gmm_grad_kernel(
    const float* __restrict__ kps,      // [B,N,3]
    const float* __restrict__ means,    // [N,K,3]
    const float* __restrict__ covs,     // [N,K,3,3]
    const float* __restrict__ weights,  // [N,K]
    float* __restrict__ out)            // [2*B*N*3]
{
    // consts[k][n][j]: j = m0,m1,m2,p00,p01,p02,p11,p12,p22,cp
    // stride between n = 10 floats (40B): b64 starts at banks gcd(10,32)=2
    // -> 2-way alias (free).
    __shared__ float consts[KK][32][10];
    const int tid = threadIdx.x;
    const int n = tid & 31;

    // ---- issue kps loads FIRST so HBM latency overlaps setup ----
    const long pair0 = (long)blockIdx.x * (256 * RR) + tid;
    float x0[RR], x1[RR], x2[RR];
#pragma unroll
    for (int r = 0; r < RR; ++r) {
        const float* src = kps + (pair0 + r * 256) * 3;
        x0[r] = src[0];
        x1[r] = src[1];
        x2[r] = src[2];
    }

    // ---- setup: cofactor inverse of SPD 3x3, fold scales ----
    {
        const int k1 = tid >> 5;  // 0..7; handle k1 and k1+8
#pragma unroll
        for (int kk = 0; kk < 2; ++kk) {
            const int k = k1 + kk * 8;
            const int p = n * KK + k;
            const float* C = covs + p * 9;
            const float a = C[0], b = C[1], c = C[2];
            const float d = C[4], e = C[5], f = C[8];
            const float i00 = d * f - e * e;
            const float i01 = c * e - b * f;
            const float i02 = b * e - c * d;
            const float i11 = a * f - c * c;
            const float i12 = b * c - a * e;
            const float i22 = a * d - b * b;
            const float det = a * i00 + b * i01 + c * i02;  // > 0 (SPD)
            const float rs = S_FOLD / det;
            const float logdet = __logf(det);
            const float w = weights[p];
            const float cp = (__logf(w) - 0.5f * (3.0f * LN2PI + logdet)) * LOG2E;
            const float* m = means + p * 3;
            float* dst = consts[k][n];
            dst[0] = m[0];
            dst[1] = m[1];
            dst[2] = m[2];
            dst[3] = i00 * rs;
            dst[4] = i01 * rs;
            dst[5] = i02 * rs;
            dst[6] = i11 * rs;
            dst[7] = i12 * rs;
            dst[8] = i22 * rs;
            dst[9] = cp;
        }
    }
    __syncthreads();

    float pdf[RR], g0[RR], g1[RR], g2[RR];
#pragma unroll
    for (int r = 0; r < RR; ++r) { pdf[r] = 0.f; g0[r] = 0.f; g1[r] = 0.f; g2[r] = 0.f; }

#pragma unroll
    for (int k = 0; k < KK; ++k) {
        const float2* L = reinterpret_cast<const float2*>(consts[k][n]);
        const float2 c0 = L[0];  // m0  m1
        const float2 c1 = L[1];  // m2  p00
        const float2 c2 = L[2];  // p01 p02
        const float2 c3 = L[3];  // p11 p12
        const float2 c4 = L[4];  // p22 cp
        const float m0 = c0.x, m1 = c0.y, m2 = c1.x;
        const float p00 = c1.y, p01 = c2.x, p02 = c2.y;
        const float p11 = c3.x, p12 = c3.y, p22 = c4.x;
        const float cp = c4.y;
#pragma unroll
        for (int r = 0; r < RR; ++r) {
            const float d0 = x0[r] - m0;
            const float d1 = x1[r] - m1;
            const float d2 = x2[r] - m2;
            // pd' = (0.5*log2e) * Sigma^{-1} d   (scale folded into P')
            const float pd0 = fmaf(p00, d0, fmaf(p01, d1, p02 * d2));
            const float pd1 = fmaf(p01, d0, fmaf(p11, d1, p12 * d2));
            const float pd2 = fmaf(p02, d0, fmaf(p12, d1, p22 * d2));
            const float mh = fmaf(pd0, d0, fmaf(pd1, d1, pd2 * d2));
            const float ec = EXP2F(cp - mh);  // = w_k * N(x; mu, Sigma)
            pdf[r] += ec;
            g0[r] = fmaf(ec, pd0, g0[r]);
            g1[r] = fmaf(ec, pd1, g1[r]);
            g2[r] = fmaf(ec, pd2, g2[r]);
        }
    }

    const long half = (long)BB * NN * 3;
#pragma unroll
    for (int r = 0; r < RR; ++r) {
        const long pair = pair0 + r * 256;
        // density: sigmoid((pdf - 40)/7.5)
        const float z = (pdf[r] - 40.0f) * (1.0f / 7.5f);
        const float dens = 1.0f / (1.0f + __expf(-z));
        // gradient: true grad = -gs/s; direction = -gs/|gs| (s cancels);
        // gnorm_true = |gs| * (2 ln2)
        const float q2 = fmaf(g0[r], g0[r], fmaf(g1[r], g1[r], g2[r] * g2[r]));
        const float q = sqrtf(q2);
        const float gnorm = q * INV_S;
        const float mag = __expf((5500.0f - gnorm) * (1.0f / 1100.0f));
        const float coef = -mag / q;
        float* od = out + pair * 3;
        od[0] = dens;
        od[1] = dens;
        od[2] = dens;
        float* og = out + half + pair * 3;
        og[0] = g0[r] * coef;
        og[1] = g1[r] * coef;
        og[2] = g2[r] * coef;
    }
}

extern "C" void kernel_launch(void* const* d_in, const int* in_sizes, int n_in,
                              void* d_out, int out_size, void* d_ws, size_t ws_size,
                              hipStream_t stream) {
    const float* kps = (const float*)d_in[0];      // [B,N,3]
    const float* means = (const float*)d_in[1];    // [N,K,3]
    const float* covs = (const float*)d_in[2];     // [N,K,3,3]
    const float* weights = (const float*)d_in[3];  // [N,K]
    float* out = (float*)d_out;

    // B*N = 524288 pairs; 512 pairs/block (256 threads x RR)
    const int grid = (BB * NN) / (256 * RR);  // 1024
    gmm_grad_kernel<<<grid, 256, 0, stream>>>(kps, means, covs, weights, out);
}

// Round 3
// 14.027 us; speedup vs baseline: 1.2125x; 1.1552x over previous
//
#include <hip/hip_runtime.h>

// GMMGradient: B=16384 samples, N=32 keypoints, K=16 components, D=3.
// out[0 .. B*N*D)          = sigmoid((pdf-40)/7.5) repeated 3x per (b,n)
// out[B*N*D .. 2*B*N*D)    = grad/|grad| * exp((5500-|grad|)/1100)
//
// R2: pack the 2 samples/thread into <2 x float> so the main loop emits
// v_pk_fma_f32 (2x fp32 rate on CDNA4); fast rcp/rsq/exp2 epilogue instead
// of IEEE-precise div/sqrt expansions; all-log2 constant folding.

#define BB 16384
#define NN 32
#define KK 16
#define RR 2   // samples per thread == pack width

typedef float f32x2 __attribute__((ext_vector_type(2)));

#define S_FOLD   0.7213475204444817f   // 0.5 * log2(e); folded into precision
#define LOG2_2PI 2.6514961294723187f   // log2(2*pi)
#define LOG2E    1.4426950408889634f

static __device__ __forceinline__ float fexp2(float x) { return __builtin_amdgcn_exp2f(x); }
static __device__ __forceinline__ float flog2(float x) { return __builtin_amdgcn_logf(x); }
static __device__ __forceinline__ float frcp(float x)  { return __builtin_amdgcn_rcpf(x); }
static __device__ __forceinline__ float frsq(float x)  { return __builtin_amdgcn_rsqf(x); }

static __device__ __forceinline__ f32x2 sp(float v) { f32x2 r; r.x = v; r.y = v; return r; }
static __device__ __forceinline__ f32x2 fma2(f32x2 a, f32x2 b, f32x2 c) {
    return __builtin_elementwise_fma(a, b, c);
}

__global__ __launch_bounds__(256) void gmm_grad_kernel(
    const float* __restrict__ kps,      // [B,N,3]
    const float* __restrict__ means,    // [N,K,3]
    const float* __restrict__ covs,     // [N,K,3,3]
    const float* __restrict__ weights,  // [N,K]
    float* __restrict__ out)            // [2*B*N*3]
{
    // consts[k][n][j]: j = m0,m1,m2,p00,p01,p02,p11,p12,p22,cp
    // lane stride 40B -> b64 reads land 2 lanes/bank (free, m136).
    __shared__ float consts[KK][32][10];
    const int tid = threadIdx.x;
    const int n = tid & 31;

    // ---- issue kps loads FIRST so HBM latency overlaps setup ----
    const long pair0 = (long)blockIdx.x * (256 * RR) + tid;
    const float* s0 = kps + pair0 * 3;
    const float* s1 = kps + (pair0 + 256) * 3;
    f32x2 X0, X1, X2;
    X0.x = s0[0]; X1.x = s0[1]; X2.x = s0[2];
    X0.y = s1[0]; X1.y = s1[1]; X2.y = s1[2];

    // ---- setup: cofactor inverse of SPD 3x3, fold scales (all in log2) ----
    {
        const int k1 = tid >> 5;  // 0..7; handle k1 and k1+8
#pragma unroll
        for (int kk = 0; kk < 2; ++kk) {
            const int k = k1 + kk * 8;
            const int p = n * KK + k;
            const float* C = covs + p * 9;
            const float a = C[0], b = C[1], c = C[2];
            const float d = C[4], e = C[5], f = C[8];
            const float i00 = d * f - e * e;
            const float i01 = c * e - b * f;
            const float i02 = b * e - c * d;
            const float i11 = a * f - c * c;
            const float i12 = b * c - a * e;
            const float i22 = a * d - b * b;
            const float det = a * i00 + b * i01 + c * i02;  // > 0 (SPD)
            const float rs = S_FOLD * frcp(det);
            const float w = weights[p];
            // cp = log2(w) - 0.5*(3*log2(2pi) + log2(det))
            const float cp = flog2(w) - 0.5f * fmaf(3.0f, LOG2_2PI, flog2(det));
            const float* m = means + p * 3;
            float* dst = consts[k][n];
            dst[0] = m[0];
            dst[1] = m[1];
            dst[2] = m[2];
            dst[3] = i00 * rs;
            dst[4] = i01 * rs;
            dst[5] = i02 * rs;
            dst[6] = i11 * rs;
            dst[7] = i12 * rs;
            dst[8] = i22 * rs;
            dst[9] = cp;
        }
    }
    __syncthreads();

    f32x2 pdf = sp(0.f), G0 = sp(0.f), G1 = sp(0.f), G2 = sp(0.f);

#pragma unroll
    for (int k = 0; k < KK; ++k) {
        const float2* L = reinterpret_cast<const float2*>(consts[k][n]);
        const float2 c0 = L[0];  // m0  m1
        const float2 c1 = L[1];  // m2  p00
        const float2 c2 = L[2];  // p01 p02
        const float2 c3 = L[3];  // p11 p12
        const float2 c4 = L[4];  // p22 cp
        const float m0 = c0.x, m1 = c0.y, m2 = c1.x;
        const float p00 = c1.y, p01 = c2.x, p02 = c2.y;
        const float p11 = c3.x, p12 = c3.y, p22 = c4.x;
        const float cp = c4.y;

        const f32x2 d0 = X0 - sp(m0);
        const f32x2 d1 = X1 - sp(m1);
        const f32x2 d2 = X2 - sp(m2);
        // pd' = (0.5*log2e) * Sigma^{-1} d   (scale folded into P')
        const f32x2 pd0 = fma2(sp(p00), d0, fma2(sp(p01), d1, sp(p02) * d2));
        const f32x2 pd1 = fma2(sp(p01), d0, fma2(sp(p11), d1, sp(p12) * d2));
        const f32x2 pd2 = fma2(sp(p02), d0, fma2(sp(p12), d1, sp(p22) * d2));
        const f32x2 mh  = fma2(pd0, d0, fma2(pd1, d1, pd2 * d2));
        f32x2 ec;
        ec.x = fexp2(cp - mh.x);  // = w_k * N(x; mu, Sigma)
        ec.y = fexp2(cp - mh.y);
        pdf += ec;
        G0 = fma2(ec, pd0, G0);
        G1 = fma2(ec, pd1, G1);
        G2 = fma2(ec, pd2, G2);
    }

    const long half = (long)BB * NN * 3;
#pragma unroll
    for (int r = 0; r < RR; ++r) {
        const long pair = pair0 + r * 256;
        const float pf = r ? pdf.y : pdf.x;
        const float g0 = r ? G0.y : G0.x;
        const float g1 = r ? G1.y : G1.x;
        const float g2 = r ? G2.y : G2.x;
        // density: sigmoid((pdf - 40)/7.5) = rcp(1 + exp2(-z*log2e))
        const float z = (pf - 40.0f) * (1.0f / 7.5f);
        const float dens = frcp(1.0f + fexp2(-z * LOG2E));
        // gradient: true grad = -gs/s; direction = -gs/|gs| (s cancels);
        // gnorm_true = |gs| * 2ln2; mag exponent folds to 5*log2e - q/550
        const float q2 = fmaf(g0, g0, fmaf(g1, g1, g2 * g2));
        const float rq = frsq(q2);
        const float q = q2 * rq;  // |gs|
        const float mag = fexp2(fmaf(q, -(1.0f / 550.0f), 5.0f * LOG2E));
        const float coef = -mag * rq;
        float* od = out + pair * 3;
        od[0] = dens;
        od[1] = dens;
        od[2] = dens;
        float* og = out + half + pair * 3;
        og[0] = g0 * coef;
        og[1] = g1 * coef;
        og[2] = g2 * coef;
    }
}

extern "C" void kernel_launch(void* const* d_in, const int* in_sizes, int n_in,
                              void* d_out, int out_size, void* d_ws, size_t ws_size,
                              hipStream_t stream) {
    const float* kps = (const float*)d_in[0];      // [B,N,3]
    const float* means = (const float*)d_in[1];    // [N,K,3]
    const float* covs = (const float*)d_in[2];     // [N,K,3,3]
    const float* weights = (const float*)d_in[3];  // [N,K]
    float* out = (float*)d_out;

    // B*N = 524288 pairs; 512 pairs/block (256 threads x RR)
    const int grid = (BB * NN) / (256 * RR);  // 1024
    gmm_grad_kernel<<<grid, 256, 0, stream>>>(kps, means, covs, weights, out);
}

// Round 4
// 13.215 us; speedup vs baseline: 1.2870x; 1.0614x over previous
//
#include <hip/hip_runtime.h>

// GMMGradient: B=16384 samples, N=32 keypoints, K=16 components, D=3.
// out[0 .. B*N*D)          = sigmoid((pdf-40)/7.5) repeated 3x per (b,n)
// out[B*N*D .. 2*B*N*D)    = grad/|grad| * exp((5500-|grad|)/1100)
//
// R3: BLOCK=512 (one 3x3 inversion per thread, half the total setup work),
// dwordx3 kps loads and dwordx3 stores (float3), packed f32x2 main loop,
// fast rcp/rsq/exp2 epilogue. Model: dur = ~10.5us replay overhead +
// kernel ~3us (HBM floor 18.9 MB @ ~6.9 TB/s).

#define BB 16384
#define NN 32
#define KK 16
#define RR 2    // samples per thread == pack width
#define BLK 512

typedef float f32x2 __attribute__((ext_vector_type(2)));

#define S_FOLD   0.7213475204444817f   // 0.5 * log2(e); folded into precision
#define LOG2_2PI 2.6514961294723187f   // log2(2*pi)
#define LOG2E    1.4426950408889634f

static __device__ __forceinline__ float fexp2(float x) { return __builtin_amdgcn_exp2f(x); }
static __device__ __forceinline__ float flog2(float x) { return __builtin_amdgcn_logf(x); }
static __device__ __forceinline__ float frcp(float x)  { return __builtin_amdgcn_rcpf(x); }
static __device__ __forceinline__ float frsq(float x)  { return __builtin_amdgcn_rsqf(x); }

static __device__ __forceinline__ f32x2 sp(float v) { f32x2 r; r.x = v; r.y = v; return r; }
static __device__ __forceinline__ f32x2 fma2(f32x2 a, f32x2 b, f32x2 c) {
    return __builtin_elementwise_fma(a, b, c);
}

struct F3 { float x, y, z; };  // 12B, align 4 -> global_load/store_dwordx3

__global__ __launch_bounds__(BLK) void gmm_grad_kernel(
    const float* __restrict__ kps,      // [B,N,3]
    const float* __restrict__ means,    // [N,K,3]
    const float* __restrict__ covs,     // [N,K,3,3]
    const float* __restrict__ weights,  // [N,K]
    float* __restrict__ out)            // [2*B*N*3]
{
    // consts[k][n][j]: j = m0,m1,m2,p00,p01,p02,p11,p12,p22,cp
    // lane stride 40B -> b64 reads land 2 lanes/bank (free, m136).
    __shared__ float consts[KK][32][10];
    const int tid = threadIdx.x;
    const int n = tid & 31;

    // ---- issue kps loads FIRST so HBM latency overlaps setup ----
    const long pair0 = (long)blockIdx.x * (BLK * RR) + tid;
    const F3* __restrict__ kp3 = reinterpret_cast<const F3*>(kps);
    const F3 a0 = kp3[pair0];
    const F3 a1 = kp3[pair0 + BLK];
    f32x2 X0, X1, X2;
    X0.x = a0.x; X1.x = a0.y; X2.x = a0.z;
    X0.y = a1.x; X1.y = a1.y; X2.y = a1.z;

    // ---- setup: one cofactor inverse of SPD 3x3 per thread (512 = K*N) ----
    {
        const int k = tid >> 5;   // 0..15
        const int p = n * KK + k;
        const float* C = covs + p * 9;
        const float a = C[0], b = C[1], c = C[2];
        const float d = C[4], e = C[5], f = C[8];
        const float i00 = d * f - e * e;
        const float i01 = c * e - b * f;
        const float i02 = b * e - c * d;
        const float i11 = a * f - c * c;
        const float i12 = b * c - a * e;
        const float i22 = a * d - b * b;
        const float det = a * i00 + b * i01 + c * i02;  // > 0 (SPD)
        const float rs = S_FOLD * frcp(det);
        const float w = weights[p];
        // cp = log2(w) - 0.5*(3*log2(2pi) + log2(det))
        const float cp = flog2(w) - 0.5f * fmaf(3.0f, LOG2_2PI, flog2(det));
        const float* m = means + p * 3;
        float* dst = consts[k][n];
        dst[0] = m[0];
        dst[1] = m[1];
        dst[2] = m[2];
        dst[3] = i00 * rs;
        dst[4] = i01 * rs;
        dst[5] = i02 * rs;
        dst[6] = i11 * rs;
        dst[7] = i12 * rs;
        dst[8] = i22 * rs;
        dst[9] = cp;
    }
    __syncthreads();

    f32x2 pdf = sp(0.f), G0 = sp(0.f), G1 = sp(0.f), G2 = sp(0.f);

#pragma unroll
    for (int k = 0; k < KK; ++k) {
        const float2* L = reinterpret_cast<const float2*>(consts[k][n]);
        const float2 c0 = L[0];  // m0  m1
        const float2 c1 = L[1];  // m2  p00
        const float2 c2 = L[2];  // p01 p02
        const float2 c3 = L[3];  // p11 p12
        const float2 c4 = L[4];  // p22 cp
        const float m0 = c0.x, m1 = c0.y, m2 = c1.x;
        const float p00 = c1.y, p01 = c2.x, p02 = c2.y;
        const float p11 = c3.x, p12 = c3.y, p22 = c4.x;
        const float cp = c4.y;

        const f32x2 d0 = X0 - sp(m0);
        const f32x2 d1 = X1 - sp(m1);
        const f32x2 d2 = X2 - sp(m2);
        // pd' = (0.5*log2e) * Sigma^{-1} d   (scale folded into P')
        const f32x2 pd0 = fma2(sp(p00), d0, fma2(sp(p01), d1, sp(p02) * d2));
        const f32x2 pd1 = fma2(sp(p01), d0, fma2(sp(p11), d1, sp(p12) * d2));
        const f32x2 pd2 = fma2(sp(p02), d0, fma2(sp(p12), d1, sp(p22) * d2));
        const f32x2 mh  = fma2(pd0, d0, fma2(pd1, d1, pd2 * d2));
        f32x2 ec;
        ec.x = fexp2(cp - mh.x);  // = w_k * N(x; mu, Sigma)
        ec.y = fexp2(cp - mh.y);
        pdf += ec;
        G0 = fma2(ec, pd0, G0);
        G1 = fma2(ec, pd1, G1);
        G2 = fma2(ec, pd2, G2);
    }

    const long half = (long)BB * NN;  // in F3 units
    F3* __restrict__ out3 = reinterpret_cast<F3*>(out);
#pragma unroll
    for (int r = 0; r < RR; ++r) {
        const long pair = pair0 + r * BLK;
        const float pf = r ? pdf.y : pdf.x;
        const float g0 = r ? G0.y : G0.x;
        const float g1 = r ? G1.y : G1.x;
        const float g2 = r ? G2.y : G2.x;
        // density: sigmoid((pdf - 40)/7.5) = rcp(1 + exp2(-z*log2e))
        const float z = (pf - 40.0f) * (1.0f / 7.5f);
        const float dens = frcp(1.0f + fexp2(-z * LOG2E));
        // gradient: true grad = -gs/s; direction = -gs/|gs| (s cancels);
        // gnorm_true = |gs| * 2ln2; mag exponent folds to 5*log2e - q/550
        const float q2 = fmaf(g0, g0, fmaf(g1, g1, g2 * g2));
        const float rq = frsq(q2);
        const float q = q2 * rq;  // |gs|
        const float mag = fexp2(fmaf(q, -(1.0f / 550.0f), 5.0f * LOG2E));
        const float coef = -mag * rq;
        F3 od; od.x = dens; od.y = dens; od.z = dens;
        F3 og; og.x = g0 * coef; og.y = g1 * coef; og.z = g2 * coef;
        out3[pair] = od;
        out3[half + pair] = og;
    }
}

extern "C" void kernel_launch(void* const* d_in, const int* in_sizes, int n_in,
                              void* d_out, int out_size, void* d_ws, size_t ws_size,
                              hipStream_t stream) {
    const float* kps = (const float*)d_in[0];      // [B,N,3]
    const float* means = (const float*)d_in[1];    // [N,K,3]
    const float* covs = (const float*)d_in[2];     // [N,K,3,3]
    const float* weights = (const float*)d_in[3];  // [N,K]
    float* out = (float*)d_out;

    // B*N = 524288 pairs; 1024 pairs/block (512 threads x RR)
    const int grid = (BB * NN) / (BLK * RR);  // 512
    gmm_grad_kernel<<<grid, BLK, 0, stream>>>(kps, means, covs, weights, out);
}